// Round 10
// baseline (105.348 us; speedup 1.0000x reference)
//
#include <hip/hip_runtime.h>
#include <hip/hip_bf16.h>

#define BATCH 8
#define SEQ   2048
#define DIM   64
#define TSPLIT 8

typedef __attribute__((ext_vector_type(8))) short short8;
typedef __attribute__((ext_vector_type(4))) float floatx4;

// fast f32->bf16: +0x8000 then truncate (<=0.5ulp + 2^-17 bias; bf16 already 0.4% quant)
static __device__ __forceinline__ unsigned short f2bf(float x) {
    union { float f; unsigned u; } v; v.f = x;
    return (unsigned short)((v.u + 0x8000u) >> 16);
}

#if __has_builtin(__builtin_amdgcn_sqrtf)
#define FSQRT(x) __builtin_amdgcn_sqrtf(x)
#else
#define FSQRT(x) sqrtf(x)
#endif
#if __has_builtin(__builtin_amdgcn_exp2f)
#define FEXP2(x) __builtin_amdgcn_exp2f(x)
#else
#define FEXP2(x) exp2f(x)
#endif

// async global->LDS DMA, 16 B/lane; LDS dest = wave-uniform base + lane*16
static __device__ __forceinline__ void load_lds16(const void* g, void* l) {
    __builtin_amdgcn_global_load_lds(
        (const __attribute__((address_space(1))) void*)g,
        (__attribute__((address_space(3))) void*)l, 16, 0, 0);
}

// ---- fused prep ------------------------------------------------------------
// blocks [0,512): Q/K bf16 cast + row norms; Q holds -2q; K chunk-swizzled.
// blocks [512,768): V -> Vt[b][d][t] transpose (chunk-swizzled per 64-key
//   slice) + PER-TILE column-sum partials (csum_part[b][32][64], no atomics).
#define QK_BLK 512
#define VT_BLK 256

__global__ __launch_bounds__(256) void prep_all(
        const float* __restrict__ Q, const float* __restrict__ K,
        const float* __restrict__ V,
        unsigned short* __restrict__ Qb, unsigned short* __restrict__ Kb,
        unsigned short* __restrict__ Vt,
        float* __restrict__ q2, float* __restrict__ k2,
        float* __restrict__ csum_part) {
    int bid = blockIdx.x;
    if (bid < QK_BLK) {
        const int NQ = BATCH * SEQ * (DIM / 4);   // 262144 float4s in Q
        #pragma unroll
        for (int ch = 0; ch < 4; ++ch) {
            int gid = ch * (QK_BLK * 256) + bid * 256 + threadIdx.x;
            const float* src; unsigned short* db; float* dn; int idx; float scl; int swz;
            if (gid < NQ) { src = Q; db = Qb; dn = q2; idx = gid;      scl = -2.f; swz = 0; }
            else          { src = K; db = Kb; dn = k2; idx = gid - NQ; scl =  1.f; swz = 1; }
            float4 v = ((const float4*)src)[idx];
            float s = v.x * v.x + v.y * v.y + v.z * v.z + v.w * v.w;   // norm of RAW row
            ushort4 o;
            o.x = f2bf(v.x * scl); o.y = f2bf(v.y * scl);
            o.z = f2bf(v.z * scl); o.w = f2bf(v.w * scl);
            int row = idx >> 4, j = idx & 15;
            int jo  = swz ? (j ^ ((row & 7) << 1)) : j;   // 16B-chunk XOR swizzle
            ((ushort4*)db)[(row << 4) | jo] = o;
            s += __shfl_xor(s, 1); s += __shfl_xor(s, 2);
            s += __shfl_xor(s, 4); s += __shfl_xor(s, 8);
            if (j == 0) dn[row] = s;
        }
    } else {
        __shared__ float tile[64][65];
        __shared__ float psum[4][64];
        int vb = bid - QK_BLK;                    // vb = b*32 + tile
        int b  = vb >> 5;
        int t0 = (vb & 31) * 64;
        int i  = threadIdx.x;
        int d  = i & 63, g = i >> 6;
        float part = 0.f;
        #pragma unroll
        for (int p = 0; p < 16; ++p) {
            int tt = p * 4 + g;
            float v = V[((size_t)(b * SEQ + t0 + tt)) * DIM + d];
            tile[tt][d] = v;
            part += v;
        }
        psum[g][d] = part;
        __syncthreads();
        int tt = i & 63;
        #pragma unroll
        for (int p = 0; p < 16; ++p) {
            int dd = p * 4 + g;
            // chunk swizzle within the 64-key (128 B) slice
            Vt[((size_t)(b * DIM + dd)) * SEQ + t0 + (tt ^ ((dd & 7) << 3))] =
                f2bf(tile[tt][dd]);
        }
        if (i < 64)
            csum_part[vb * 64 + i] =
                psum[0][i] + psum[1][i] + psum[2][i] + psum[3][i];
    }
}

// ---- main: shifted-softmax gaussian attention ------------------------------
// r9 post-mortem: ts x4 gave only 49.5->~33us; LDS 40960B pads to 41984 ->
// 3 blocks/CU. This round: ts x8 (grid 2048), SINGLE-buffered 64-key tile
// (Kt 8K + Vv 8K + P 8K = 24576B -> 6 blocks/CU = 24 waves/CU). Per-block DMA
// drain is covered by the other 5 blocks' compute (m114 co-scheduling).
// Partials to nbuf[ts]/dbuf[ts] with plain stores -- no atomics, no memsets.
__global__ __launch_bounds__(256, 6) void gauss_attn(
        const unsigned short* __restrict__ Qb, const unsigned short* __restrict__ Kb,
        const unsigned short* __restrict__ Vt, const float* __restrict__ q2,
        const float* __restrict__ k2,
        float* __restrict__ nbuf, float* __restrict__ dbuf) {
    __shared__ __align__(16) struct {
        unsigned short Kt[64 * 64];      // 8 KB (K tile, unpadded, swizzled)
        unsigned short Vv[64 * 64];      // 8 KB (V tile, unpadded, swizzled)
        unsigned short P[4][16 * 64];    // 8 KB (per-wave P', chunk-swizzled)
    } sh;                                // = 24576 B

    const int bid   = blockIdx.x;                 // grid = 8 * 32 * 8
    const int ts    = bid & 7;                    // key eighth
    const int qt    = (bid >> 3) & 31;            // 64-row q tile
    const int b     = bid >> 8;
    const int tid   = threadIdx.x;
    const int w     = tid >> 6;
    const int lane  = tid & 63;
    const int l15   = lane & 15;
    const int quad  = lane >> 4;
    const int qrow0 = qt * 64 + w * 16;           // this wave's 16 q-rows
    const int s7    = l15 & 7;                    // fragment de-swizzle key
    const int t00   = ts * 256;                   // this block's 256 keys

    const size_t kbase = (size_t)b * SEQ * DIM;   // shorts
    const size_t vbase = (size_t)b * DIM * SEQ;

    // Q fragments (A operand, holds -2q): A[m=lane&15][k=quad*8+j]
    short8 qf0 = *(const short8*)(Qb + ((size_t)(b * SEQ + qrow0 + l15)) * DIM + quad * 8);
    short8 qf1 = *(const short8*)(Qb + ((size_t)(b * SEQ + qrow0 + l15)) * DIM + 32 + quad * 8);
    floatx4 q2v = *(const floatx4*)(q2 + b * SEQ + qrow0 + quad * 4);
    const float* k2p = k2 + b * SEQ + l15;

    floatx4 acc[4];
    #pragma unroll
    for (int nt = 0; nt < 4; ++nt) acc[nt] = (floatx4){0.f, 0.f, 0.f, 0.f};
    float dsum[4] = {0.f, 0.f, 0.f, 0.f};

    unsigned short* Pw = sh.P[w];
    const float NLOG2E = -1.4426950408889634f;

    // per-tile DMA: wave w stages its 16 K-rows and 16 V(d)-rows; 8 rows/instr
    auto dma_tile = [&](int t0) {
        #pragma unroll
        for (int i = 0; i < 2; ++i) {
            int r = w * 16 + i * 8;
            load_lds16(Kb + kbase + (size_t)(t0 + r + (lane >> 3)) * DIM + (lane & 7) * 8,
                       &sh.Kt[r * 64]);
            load_lds16(Vt + vbase + (size_t)(r + (lane >> 3)) * SEQ + t0 + (lane & 7) * 8,
                       &sh.Vv[r * 64]);
        }
    };

    #pragma unroll 1
    for (int it = 0; it < 4; ++it) {
        const int t0 = t00 + it * 64;
        __syncthreads();               // previous tile fully consumed
        dma_tile(t0);
        __syncthreads();               // DMA drained (compiler inserts vmcnt(0))

        float k2n0 = k2p[t0], k2n1 = k2p[t0 + 16], k2n2 = k2p[t0 + 32], k2n3 = k2p[t0 + 48];

        // ---- QK^T (C seeded with q2+k2 -> d2 out of the MFMA) + scoring ----
        #pragma unroll
        for (int nt = 0; nt < 4; ++nt) {
            short8 kf0 = *(const short8*)&sh.Kt[(nt * 16 + l15) * 64 + ((quad ^ s7) << 3)];
            short8 kf1 = *(const short8*)&sh.Kt[(nt * 16 + l15) * 64 + (((4 | quad) ^ s7) << 3)];
            float k2n = (nt == 0) ? k2n0 : (nt == 1) ? k2n1 : (nt == 2) ? k2n2 : k2n3;
            floatx4 sc;
            #pragma unroll
            for (int r = 0; r < 4; ++r) sc[r] = q2v[r] + k2n;
            sc = __builtin_amdgcn_mfma_f32_16x16x32_bf16(qf0, kf0, sc, 0, 0, 0);
            sc = __builtin_amdgcn_mfma_f32_16x16x32_bf16(qf1, kf1, sc, 0, 0, 0);
            #pragma unroll
            for (int r = 0; r < 4; ++r) {
                float d2  = fmaxf(sc[r], 0.f);
                float wgt = FEXP2(FSQRT(d2) * NLOG2E);           // exp(-dist)
                // expm1(wgt) cubic series; wgt < 3e-3 at 5 sigma -> err < 1e-11
                float pv = wgt * fmaf(wgt, fmaf(wgt, 0.16666667f, 0.5f), 1.f);
                dsum[r] += pv;
                int row = quad * 4 + r;
                // chunk-swizzled P store: chunk (nt*2 | l15>>3) -> ^(row&7)
                Pw[row * 64 + ((((nt << 1) | (l15 >> 3)) ^ (row & 7)) << 3) + (l15 & 7)]
                    = f2bf(pv);
            }
        }

        // ---- P'V from LDS tiles (pf read de-swizzles with l15&7) ----
        #pragma unroll
        for (int tc = 0; tc < 2; ++tc) {
            short8 pf = *(const short8*)&Pw[l15 * 64 + (((tc * 4 + quad) ^ s7) << 3)];
            #pragma unroll
            for (int nt = 0; nt < 4; ++nt) {
                short8 vf = *(const short8*)
                    &sh.Vv[(nt * 16 + l15) * 64 + ((((tc << 2) | quad) ^ s7) << 3)];
                acc[nt] = __builtin_amdgcn_mfma_f32_16x16x32_bf16(pf, vf, acc[nt], 0, 0, 0);
            }
        }
    }

    // ---- partial epilogue: plain stores to this split's buffers ----
    #pragma unroll
    for (int r = 0; r < 4; ++r) {
        dsum[r] += __shfl_xor(dsum[r], 1);
        dsum[r] += __shfl_xor(dsum[r], 2);
        dsum[r] += __shfl_xor(dsum[r], 4);
        dsum[r] += __shfl_xor(dsum[r], 8);
    }
    float* nb = nbuf + (size_t)ts * (BATCH * SEQ * DIM);
    #pragma unroll
    for (int nt = 0; nt < 4; ++nt) {
        #pragma unroll
        for (int r = 0; r < 4; ++r) {
            nb[((size_t)(b * SEQ + qrow0 + quad * 4 + r)) * DIM + nt * 16 + l15] =
                acc[nt][r];
        }
    }
    if (l15 == 0) {
        #pragma unroll
        for (int r = 0; r < 4; ++r)
            dbuf[ts * (BATCH * SEQ) + b * SEQ + qrow0 + quad * 4 + r] = dsum[r];
    }
}

// ---- finalize: out = (sum_ts nbuf + sum_t csum_part) / (S + sum_ts dbuf) ---
__global__ __launch_bounds__(256) void finalize(
        const float* __restrict__ nbuf, const float* __restrict__ dbuf,
        const float* __restrict__ csum_part, float* __restrict__ out) {
    int gid = blockIdx.x * 256 + threadIdx.x;   // one float4 of d per thread
    int row = gid >> 4;                          // b*SEQ + s
    int dq  = gid & 15;
    int b   = row >> 11;
    float den = 2048.f;
    #pragma unroll
    for (int t = 0; t < TSPLIT; ++t) den += dbuf[t * (BATCH * SEQ) + row];
    float rcp = 1.f / den;
    float4 n = {0.f, 0.f, 0.f, 0.f};
    #pragma unroll
    for (int t = 0; t < TSPLIT; ++t) {
        float4 p = *(const float4*)(nbuf + (size_t)t * (BATCH * SEQ * DIM)
                                         + (size_t)row * DIM + dq * 4);
        n.x += p.x; n.y += p.y; n.z += p.z; n.w += p.w;
    }
    #pragma unroll 8
    for (int t = 0; t < 32; ++t) {               // V col-sum partials (L1-hot)
        float4 c = *(const float4*)(csum_part + (b * 32 + t) * 64 + dq * 4);
        n.x += c.x; n.y += c.y; n.z += c.z; n.w += c.w;
    }
    float4 o = {n.x * rcp, n.y * rcp, n.z * rcp, n.w * rcp};
    *(float4*)(out + (size_t)row * DIM + dq * 4) = o;
}

extern "C" void kernel_launch(void* const* d_in, const int* in_sizes, int n_in,
                              void* d_out, int out_size, void* d_ws, size_t ws_size,
                              hipStream_t stream) {
    const float* Q = (const float*)d_in[0];
    const float* K = (const float*)d_in[1];
    const float* V = (const float*)d_in[2];
    float* out = (float*)d_out;

    char* ws = (char*)d_ws;                       // ws_size = 256 MiB (proven r9)
    unsigned short* Qb = (unsigned short*)(ws);                        // 2 MB
    unsigned short* Kb = (unsigned short*)(ws + (2u << 20));           // 2 MB (swizzled)
    unsigned short* Vt = (unsigned short*)(ws + (4u << 20));           // 2 MB (swizzled)
    float* q2     = (float*)(ws + (6u << 20));                         // 64 KB
    float* k2     = (float*)(ws + (6u << 20) + (64u << 10));           // 64 KB
    float* cpart  = (float*)(ws + (6u << 20) + (128u << 10));          // 64 KB
    float* dbuf   = (float*)(ws + (6u << 20) + (192u << 10));          // 512 KB
    float* nbuf   = (float*)(ws + (7u << 20));                         // 32 MB

    prep_all<<<QK_BLK + VT_BLK, 256, 0, stream>>>(
        Q, K, V, Qb, Kb, Vt, q2, k2, cpart);
    gauss_attn<<<BATCH * 32 * TSPLIT, 256, 0, stream>>>(
        Qb, Kb, Vt, q2, k2, nbuf, dbuf);
    finalize<<<(BATCH * SEQ * DIM / 4) / 256, 256, 0, stream>>>(
        nbuf, dbuf, cpart, out);
}